// Round 1
// baseline (248.547 us; speedup 1.0000x reference)
//
#include <hip/hip_runtime.h>
#include <hip/hip_bf16.h>

#define TOK 8192
#define CDIM 768
#define NH 12
#define HD 64
#define QKV_N 2304

typedef __attribute__((ext_vector_type(8))) short bf16x8;
typedef __attribute__((ext_vector_type(4))) float f32x4;
typedef unsigned short ushort_t;

__device__ __forceinline__ ushort_t f2bf(float f) {
  unsigned u = __float_as_uint(f);
  u += 0x7fffu + ((u >> 16) & 1u);
  return (ushort_t)(u >> 16);
}

__device__ __forceinline__ f32x4 mfma16(bf16x8 a, bf16x8 b, f32x4 c) {
  return __builtin_amdgcn_mfma_f32_16x16x32_bf16(a, b, c, 0, 0, 0);
}

// ---------------- LayerNorm: 1 block per token, fp32 stats, bf16 out ----------
__global__ __launch_bounds__(256) void ln_kernel(const float* __restrict__ x,
                                                 const float* __restrict__ gamma,
                                                 const float* __restrict__ beta,
                                                 ushort_t* __restrict__ xn) {
  int t = blockIdx.x;
  const float* row = x + (size_t)t * CDIM;
  float v[3];
  float s = 0.f, s2 = 0.f;
#pragma unroll
  for (int i = 0; i < 3; i++) {
    v[i] = row[threadIdx.x + 256 * i];
    s += v[i];
    s2 += v[i] * v[i];
  }
#pragma unroll
  for (int off = 32; off; off >>= 1) {
    s += __shfl_xor(s, off);
    s2 += __shfl_xor(s2, off);
  }
  __shared__ float red[8];
  int wid = threadIdx.x >> 6, lane = threadIdx.x & 63;
  if (lane == 0) { red[wid] = s; red[wid + 4] = s2; }
  __syncthreads();
  s = red[0] + red[1] + red[2] + red[3];
  s2 = red[4] + red[5] + red[6] + red[7];
  float mu = s * (1.f / CDIM);
  float var = s2 * (1.f / CDIM) - mu * mu;
  float rstd = rsqrtf(var + 1e-5f);
  ushort_t* orow = xn + (size_t)t * CDIM;
#pragma unroll
  for (int i = 0; i < 3; i++) {
    int c = threadIdx.x + 256 * i;
    orow[c] = f2bf((v[i] - mu) * rstd * gamma[c] + beta[c]);
  }
}

// -------- Weight transpose to bf16: wt[z][n][k] = W_z[k][n] ------------------
__global__ __launch_bounds__(256) void wtrans_kernel(const float* __restrict__ Wq,
                                                     const float* __restrict__ Wk,
                                                     const float* __restrict__ Wv,
                                                     const float* __restrict__ Wo,
                                                     ushort_t* __restrict__ wt) {
  const float* W = (blockIdx.z == 0) ? Wq : (blockIdx.z == 1) ? Wk
                   : (blockIdx.z == 2) ? Wv : Wo;
  __shared__ float tile[32][33];
  int tr = blockIdx.y, tc = blockIdx.x;
  int tx = threadIdx.x, ty = threadIdx.y;
#pragma unroll
  for (int j = 0; j < 4; j++) {
    int k = tr * 32 + ty + j * 8;
    tile[ty + j * 8][tx] = W[(size_t)k * CDIM + tc * 32 + tx];
  }
  __syncthreads();
  ushort_t* o = wt + (size_t)blockIdx.z * CDIM * CDIM;
#pragma unroll
  for (int j = 0; j < 4; j++) {
    int n = tc * 32 + ty + j * 8;
    o[(size_t)n * CDIM + tr * 32 + tx] = f2bf(tile[tx][ty + j * 8]);
  }
}

// -------- GEMM: C[m][n] = sum_k A[m][k]*Bt[n][k] + epilogue ------------------
// MODE 0: QKV fused (N=2304), bf16 out, bias select, +pos_embed for n<768
// MODE 1: out-proj (N=768), fp32 out, +bias +fp32 residual
template <int MODE>
__global__ __launch_bounds__(256) void gemm_kernel(
    const ushort_t* __restrict__ A, const ushort_t* __restrict__ Bt,
    const float* __restrict__ b0, const float* __restrict__ b1,
    const float* __restrict__ b2, const float* __restrict__ extra,
    void* __restrict__ outp) {
  __shared__ __align__(16) ushort_t lds_a[128][40];  // +8 pad: conflict-free frag reads
  __shared__ __align__(16) ushort_t lds_b[128][40];
  const int bn = blockIdx.x, bm = blockIdx.y;
  const int tid = threadIdx.x;
  const int lane = tid & 63, wid = tid >> 6;
  const int wr = wid >> 1, wc = wid & 1;
  const int l16 = lane & 15, lg = lane >> 4;
  f32x4 acc[4][4] = {};

  for (int k0 = 0; k0 < CDIM; k0 += 32) {
#pragma unroll
    for (int i = 0; i < 2; i++) {
      int ch = tid + 256 * i;
      int row = ch >> 2, c8 = (ch & 3) * 8;
      *reinterpret_cast<uint4*>(&lds_a[row][c8]) =
          *reinterpret_cast<const uint4*>(&A[(size_t)(bm * 128 + row) * CDIM + k0 + c8]);
      *reinterpret_cast<uint4*>(&lds_b[row][c8]) =
          *reinterpret_cast<const uint4*>(&Bt[(size_t)(bn * 128 + row) * CDIM + k0 + c8]);
    }
    __syncthreads();
    bf16x8 af[4], bfr[4];
#pragma unroll
    for (int mi = 0; mi < 4; mi++)
      af[mi] = *reinterpret_cast<const bf16x8*>(&lds_a[wr * 64 + mi * 16 + l16][8 * lg]);
#pragma unroll
    for (int ni = 0; ni < 4; ni++)
      bfr[ni] = *reinterpret_cast<const bf16x8*>(&lds_b[wc * 64 + ni * 16 + l16][8 * lg]);
#pragma unroll
    for (int mi = 0; mi < 4; mi++)
#pragma unroll
      for (int ni = 0; ni < 4; ni++)
        acc[mi][ni] = mfma16(af[mi], bfr[ni], acc[mi][ni]);
    __syncthreads();
  }

#pragma unroll
  for (int mi = 0; mi < 4; mi++)
#pragma unroll
    for (int ni = 0; ni < 4; ni++)
#pragma unroll
      for (int r = 0; r < 4; r++) {
        int grow = bm * 128 + wr * 64 + mi * 16 + 4 * lg + r;
        int gcol = bn * 128 + wc * 64 + ni * 16 + l16;
        float v = acc[mi][ni][r];
        if (MODE == 0) {
          float bias = (gcol < 768) ? b0[gcol]
                       : (gcol < 1536) ? b1[gcol - 768] : b2[gcol - 1536];
          v += bias;
          if (gcol < 768) v += extra[(size_t)grow * CDIM + gcol];
          ((ushort_t*)outp)[(size_t)grow * QKV_N + gcol] = f2bf(v);
        } else {
          v += b0[gcol] + extra[(size_t)grow * CDIM + gcol];
          ((float*)outp)[(size_t)grow * CDIM + gcol] = v;
        }
      }
}

// -------- Flash attention: 128 Q rows/block, 4 waves x 32 rows, KV tile 64 ---
__global__ __launch_bounds__(256) void attn_kernel(const ushort_t* __restrict__ QKV,
                                                   ushort_t* __restrict__ O) {
  const int qt = blockIdx.x, h = blockIdx.y, b = blockIdx.z;
  const int tid = threadIdx.x, lane = tid & 63, w = tid >> 6;
  const int l16 = lane & 15, lg = lane >> 4;
  const int tb = b * 1024 + qt * 128;
  const int co_q = h * HD, co_k = CDIM + h * HD, co_v = 2 * CDIM + h * HD;

  __shared__ __align__(16) ushort_t p_lds[128 * 64];   // XOR-swizzled
  __shared__ __align__(16) ushort_t vt_lds[64 * 64];   // V^T, XOR-swizzled

  bf16x8 qf[2][2];
#pragma unroll
  for (int mi = 0; mi < 2; mi++)
#pragma unroll
    for (int ds = 0; ds < 2; ds++)
      qf[mi][ds] = *reinterpret_cast<const bf16x8*>(
          &QKV[(size_t)(tb + w * 32 + mi * 16 + l16) * QKV_N + co_q + ds * 32 + 8 * lg]);

  float mrow[2][4], lrow[2][4];
  f32x4 oacc[2][4] = {};
#pragma unroll
  for (int mi = 0; mi < 2; mi++)
#pragma unroll
    for (int r = 0; r < 4; r++) { mrow[mi][r] = -1e30f; lrow[mi][r] = 0.f; }

  for (int kt = 0; kt < 16; kt++) {
    const int kv0 = kt * 64;
    // stage V^T (swizzled: chunk ^= d&7)
#pragma unroll
    for (int i = 0; i < 16; i++) {
      int idx = tid + 256 * i;
      int kv = idx >> 6, d = idx & 63;
      ushort_t val = QKV[(size_t)(b * 1024 + kv0 + kv) * QKV_N + co_v + d];
      vt_lds[d * 64 + ((((kv >> 3) ^ (d & 7)) << 3) | (kv & 7))] = val;
    }
    __syncthreads();

    // S = Q K^T * 1/8 ; K fragments straight from global
    f32x4 sacc[2][4] = {};
#pragma unroll
    for (int ds = 0; ds < 2; ds++) {
      bf16x8 kf[4];
#pragma unroll
      for (int ni = 0; ni < 4; ni++)
        kf[ni] = *reinterpret_cast<const bf16x8*>(
            &QKV[(size_t)(b * 1024 + kv0 + ni * 16 + l16) * QKV_N + co_k + ds * 32 + 8 * lg]);
#pragma unroll
      for (int mi = 0; mi < 2; mi++)
#pragma unroll
        for (int ni = 0; ni < 4; ni++)
          sacc[mi][ni] = mfma16(qf[mi][ds], kf[ni], sacc[mi][ni]);
    }

    // online softmax (rows live in 16-lane groups; xor 1/2/4/8 reduces a row)
#pragma unroll
    for (int mi = 0; mi < 2; mi++)
#pragma unroll
      for (int r = 0; r < 4; r++) {
        float tm = -1e30f;
#pragma unroll
        for (int ni = 0; ni < 4; ni++) {
          sacc[mi][ni][r] *= 0.125f;
          tm = fmaxf(tm, sacc[mi][ni][r]);
        }
#pragma unroll
        for (int off = 1; off < 16; off <<= 1) tm = fmaxf(tm, __shfl_xor(tm, off));
        float newm = fmaxf(mrow[mi][r], tm);
        float corr = __expf(mrow[mi][r] - newm);
        mrow[mi][r] = newm;
        float psum = 0.f;
#pragma unroll
        for (int ni = 0; ni < 4; ni++) {
          float p = __expf(sacc[mi][ni][r] - newm);
          sacc[mi][ni][r] = p;
          psum += p;
        }
#pragma unroll
        for (int off = 1; off < 16; off <<= 1) psum += __shfl_xor(psum, off);
        lrow[mi][r] = lrow[mi][r] * corr + psum;
#pragma unroll
        for (int ni = 0; ni < 4; ni++) oacc[mi][ni][r] *= corr;
      }

    // P -> LDS (bf16, swizzled); wave-private rows, no cross-wave hazard
#pragma unroll
    for (int mi = 0; mi < 2; mi++)
#pragma unroll
      for (int ni = 0; ni < 4; ni++)
#pragma unroll
        for (int r = 0; r < 4; r++) {
          int prow = w * 32 + mi * 16 + 4 * lg + r;
          int pcol = ni * 16 + l16;
          p_lds[prow * 64 + ((((pcol >> 3) ^ (prow & 7)) << 3) | (pcol & 7))] =
              f2bf(sacc[mi][ni][r]);
        }

    // O += P @ V
#pragma unroll
    for (int ks = 0; ks < 2; ks++) {
      bf16x8 pa[2], vb[4];
#pragma unroll
      for (int mi = 0; mi < 2; mi++) {
        int prow = w * 32 + mi * 16 + l16;
        int chunk = (ks * 4 + lg) ^ (prow & 7);
        pa[mi] = *reinterpret_cast<const bf16x8*>(&p_lds[prow * 64 + chunk * 8]);
      }
#pragma unroll
      for (int ni = 0; ni < 4; ni++) {
        int vrow = ni * 16 + l16;
        int chunk = (ks * 4 + lg) ^ (vrow & 7);
        vb[ni] = *reinterpret_cast<const bf16x8*>(&vt_lds[vrow * 64 + chunk * 8]);
      }
#pragma unroll
      for (int mi = 0; mi < 2; mi++)
#pragma unroll
        for (int ni = 0; ni < 4; ni++)
          oacc[mi][ni] = mfma16(pa[mi], vb[ni], oacc[mi][ni]);
    }
    __syncthreads();
  }

#pragma unroll
  for (int mi = 0; mi < 2; mi++)
#pragma unroll
    for (int ni = 0; ni < 4; ni++)
#pragma unroll
      for (int r = 0; r < 4; r++) {
        int grow = tb + w * 32 + mi * 16 + 4 * lg + r;
        int gcol = h * HD + ni * 16 + l16;
        O[(size_t)grow * CDIM + gcol] = f2bf(oacc[mi][ni][r] / lrow[mi][r]);
      }
}

extern "C" void kernel_launch(void* const* d_in, const int* in_sizes, int n_in,
                              void* d_out, int out_size, void* d_ws, size_t ws_size,
                              hipStream_t stream) {
  const float* x     = (const float*)d_in[0];
  const float* pos   = (const float*)d_in[1];
  const float* gamma = (const float*)d_in[2];
  const float* beta  = (const float*)d_in[3];
  const float* Wq    = (const float*)d_in[4];
  const float* bq    = (const float*)d_in[5];
  const float* Wk    = (const float*)d_in[6];
  const float* bk    = (const float*)d_in[7];
  const float* Wv    = (const float*)d_in[8];
  const float* bv    = (const float*)d_in[9];
  const float* Wo    = (const float*)d_in[10];
  const float* bo    = (const float*)d_in[11];
  float* out = (float*)d_out;

  ushort_t* xn   = (ushort_t*)d_ws;                    // 8192*768
  ushort_t* wt   = xn + (size_t)TOK * CDIM;            // 3072*768 (q,k,v,o transposed)
  ushort_t* qkv  = wt + (size_t)3072 * CDIM;           // 8192*2304
  ushort_t* aout = qkv + (size_t)TOK * QKV_N;          // 8192*768

  ln_kernel<<<TOK, 256, 0, stream>>>(x, gamma, beta, xn);
  wtrans_kernel<<<dim3(24, 24, 4), dim3(32, 8), 0, stream>>>(Wq, Wk, Wv, Wo, wt);
  gemm_kernel<0><<<dim3(18, 64), 256, 0, stream>>>(xn, wt, bq, bk, bv, pos, qkv);
  attn_kernel<<<dim3(8, NH, 8), 256, 0, stream>>>(qkv, aout);
  gemm_kernel<1><<<dim3(6, 64), 256, 0, stream>>>(aout, wt + (size_t)QKV_N * CDIM,
                                                  bo, nullptr, nullptr, x, out);
}